// Round 1
// baseline (200.838 us; speedup 1.0000x reference)
//
#include <hip/hip_runtime.h>
#include <hip/hip_bf16.h>
#include <stdint.h>

// Problem constants (fixed by reference)
#define T_TASKS 8
#define DM      1024      // D_MODEL
#define HID     1024      // HIDDEN
#define NC      100       // N_CLASSES
#define NCP     128       // padded classes
#define BATCH   8192
#define MPAD    9216      // 8192 + 8*128 worst-case padding, 72 tiles of 128
#define MTILES  72

typedef __bf16 bf16x8 __attribute__((ext_vector_type(8)));
typedef float  f32x4  __attribute__((ext_vector_type(4)));

__device__ __forceinline__ unsigned short f2bf(float f) {
  __hip_bfloat16 h = __float2bfloat16(f);
  return __builtin_bit_cast(unsigned short, h);
}

// ---------------------------------------------------------------------------
// Kernel 0: bucket rows by task into 128-aligned buckets. One block.
// perm[paddedRow] = original row (or -1 for padding). starts[t] = bucket base.
// ---------------------------------------------------------------------------
__global__ void bucket_kernel(const int* __restrict__ task_id,
                              int* __restrict__ perm,
                              int* __restrict__ starts) {
  __shared__ int cnt[T_TASKS];
  __shared__ int sstart[T_TASKS + 1];
  __shared__ int idx[T_TASKS];
  const int tid = threadIdx.x;
  if (tid < T_TASKS) { cnt[tid] = 0; idx[tid] = 0; }
  __syncthreads();
  for (int r = tid; r < BATCH; r += 256) atomicAdd(&cnt[task_id[r]], 1);
  for (int i = tid; i < MPAD; i += 256) perm[i] = -1;
  __syncthreads();
  if (tid == 0) {
    int off = 0;
    for (int t = 0; t < T_TASKS; ++t) {
      sstart[t] = off;
      off += (cnt[t] + 127) & ~127;
    }
    sstart[T_TASKS] = off;
    for (int t = 0; t <= T_TASKS; ++t) starts[t] = sstart[t];
  }
  __syncthreads();
  for (int r = tid; r < BATCH; r += 256) {
    int t = task_id[r];
    int s = atomicAdd(&idx[t], 1);
    perm[sstart[t] + s] = r;  // order within bucket irrelevant (scatter back later)
  }
}

// ---------------------------------------------------------------------------
// Kernel 1: gather+convert x rows into permuted bf16 buffer (zeros for pads).
// grid = MPAD blocks x 256 threads, each thread converts 4 elements.
// ---------------------------------------------------------------------------
__global__ void gather_x(const float* __restrict__ x,
                         const int* __restrict__ perm,
                         unsigned short* __restrict__ XP) {
  const int p = blockIdx.x;
  const int r = perm[p];
  const int c = threadIdx.x * 4;
  ushort4 v;
  if (r >= 0) {
    const float4 f = *(const float4*)(x + (size_t)r * DM + c);
    v.x = f2bf(f.x); v.y = f2bf(f.y); v.z = f2bf(f.z); v.w = f2bf(f.w);
  } else {
    v.x = 0; v.y = 0; v.z = 0; v.w = 0;
  }
  *(ushort4*)(XP + (size_t)p * DM + c) = v;
}

// ---------------------------------------------------------------------------
// Kernel 2: W1 [t][d][h] fp32 -> W1T [t][h][d] bf16  (LDS-tiled 64x64)
// ---------------------------------------------------------------------------
__global__ void transpose_w1(const float* __restrict__ W1,
                             unsigned short* __restrict__ W1T) {
  __shared__ unsigned short tile[64][65];
  const int t  = blockIdx.z;
  const int d0 = blockIdx.x * 64;
  const int h0 = blockIdx.y * 64;
  const int tid = threadIdx.x;
  const float* src = W1 + (size_t)t * DM * HID;
  unsigned short* dst = W1T + (size_t)t * HID * DM;
#pragma unroll
  for (int i = 0; i < 16; ++i) {
    int idx = tid + 256 * i;
    int ld = idx >> 6, lh = idx & 63;            // read coalesced in h
    tile[lh][ld] = f2bf(src[(size_t)(d0 + ld) * HID + h0 + lh]);
  }
  __syncthreads();
#pragma unroll
  for (int i = 0; i < 16; ++i) {
    int idx = tid + 256 * i;
    int lh = idx >> 6, ld = idx & 63;            // write coalesced in d
    dst[(size_t)(h0 + lh) * DM + d0 + ld] = tile[lh][ld];
  }
}

// ---------------------------------------------------------------------------
// Kernel 3: W2 [t][h][c<100] fp32 -> W2T [t][c<128][h] bf16 (pad cols w/ 0)
// ---------------------------------------------------------------------------
__global__ void transpose_w2(const float* __restrict__ W2,
                             unsigned short* __restrict__ W2T) {
  __shared__ unsigned short tile[64][65];
  const int t  = blockIdx.z;
  const int c0 = blockIdx.x * 64;
  const int h0 = blockIdx.y * 64;
  const int tid = threadIdx.x;
  const float* src = W2 + (size_t)t * HID * NC;
  unsigned short* dst = W2T + (size_t)t * NCP * HID;
#pragma unroll
  for (int i = 0; i < 16; ++i) {
    int idx = tid + 256 * i;
    int lh = idx >> 6, lc = idx & 63;            // read coalesced in c
    int c = c0 + lc;
    float f = (c < NC) ? src[(size_t)(h0 + lh) * NC + c] : 0.f;
    tile[lc][lh] = f2bf(f);
  }
  __syncthreads();
#pragma unroll
  for (int i = 0; i < 16; ++i) {
    int idx = tid + 256 * i;
    int lc = idx >> 6, lh = idx & 63;            // write coalesced in h
    dst[(size_t)(c0 + lc) * HID + h0 + lh] = tile[lc][lh];
  }
}

// ---------------------------------------------------------------------------
// GEMM core: C[128 x 128] tile = A[128 x 1024] * BT[t][n][k]^T, bf16 MFMA.
// Block = 256 threads = 4 waves in 2x2; wave = 64x64 = 4x4 MFMA 16x16x32 tiles.
// BK=64, LDS row stride 72 (pad) for conflict-light ds_read_b128.
// L1 epilogue: +b1, ReLU, store bf16 h. L2 epilogue: +b2, scatter via perm.
// ---------------------------------------------------------------------------
template <int NTOT, bool LAYER2>
__global__ __launch_bounds__(256, 2) void gemm_k(
    const unsigned short* __restrict__ Abuf,   // [MPAD][1024] bf16
    const unsigned short* __restrict__ BT,     // [T][NTOT][1024] bf16
    const float* __restrict__ bias,            // [T][HID] or [T][NC]
    const int* __restrict__ starts,            // [9]
    const int* __restrict__ perm,              // [MPAD]
    unsigned short* __restrict__ Hout,         // layer1 out (bf16)
    float* __restrict__ Out)                   // layer2 out (fp32)
{
  __shared__ __align__(16) unsigned short As[128 * 72];
  __shared__ __align__(16) unsigned short Bs[128 * 72];
  const int tid = threadIdx.x;
  const int p0  = blockIdx.x * 128;
  const int tn0 = blockIdx.y * 128;

  int task = 0;
#pragma unroll
  for (int t = 1; t < T_TASKS; ++t)
    if (p0 >= starts[t]) task = t;   // tiles beyond total compute garbage on zero rows (discarded)

  const int wave = tid >> 6;
  const int lane = tid & 63;
  const int wm   = (wave >> 1) * 64;
  const int wn   = (wave & 1) * 64;
  const int lr   = lane & 15;        // A row / B col / C col within 16-tile
  const int quad = lane >> 4;

  f32x4 acc[4][4];
#pragma unroll
  for (int i = 0; i < 4; ++i)
#pragma unroll
    for (int j = 0; j < 4; ++j) acc[i][j] = (f32x4){0.f, 0.f, 0.f, 0.f};

  const unsigned short* Ag = Abuf + (size_t)p0 * 1024;
  const unsigned short* Bg = BT + ((size_t)task * NTOT + tn0) * 1024;

  for (int k0 = 0; k0 < 1024; k0 += 64) {
#pragma unroll
    for (int i = 0; i < 4; ++i) {
      int c   = tid + 256 * i;       // 1024 16B-chunks total (A) + (B)
      int row = c >> 3;
      int col = (c & 7) * 8;
      *(uint4*)&As[row * 72 + col] = *(const uint4*)(Ag + (size_t)row * 1024 + k0 + col);
      *(uint4*)&Bs[row * 72 + col] = *(const uint4*)(Bg + (size_t)row * 1024 + k0 + col);
    }
    __syncthreads();
#pragma unroll
    for (int kk = 0; kk < 64; kk += 32) {
      bf16x8 a[4], b[4];
#pragma unroll
      for (int i = 0; i < 4; ++i)
        a[i] = *(const bf16x8*)&As[(wm + i * 16 + lr) * 72 + kk + quad * 8];
#pragma unroll
      for (int j = 0; j < 4; ++j)
        b[j] = *(const bf16x8*)&Bs[(wn + j * 16 + lr) * 72 + kk + quad * 8];
#pragma unroll
      for (int i = 0; i < 4; ++i)
#pragma unroll
        for (int j = 0; j < 4; ++j)
          acc[i][j] = __builtin_amdgcn_mfma_f32_16x16x32_bf16(a[i], b[j], acc[i][j], 0, 0, 0);
    }
    __syncthreads();
  }

  // Epilogue. C/D layout: col = lane&15, row = quad*4 + reg  [verified m89]
  if (!LAYER2) {
    const float* bv = bias + (size_t)task * HID;
#pragma unroll
    for (int i = 0; i < 4; ++i) {
#pragma unroll
      for (int r = 0; r < 4; ++r) {
        int row = p0 + wm + i * 16 + quad * 4 + r;
#pragma unroll
        for (int j = 0; j < 4; ++j) {
          int col = tn0 + wn + j * 16 + lr;
          float v = acc[i][j][r] + bv[col];
          v = v > 0.f ? v : 0.f;
          Hout[(size_t)row * HID + col] = f2bf(v);
        }
      }
    }
  } else {
    const float* bv = bias + (size_t)task * NC;
#pragma unroll
    for (int i = 0; i < 4; ++i) {
#pragma unroll
      for (int r = 0; r < 4; ++r) {
        int prow = p0 + wm + i * 16 + quad * 4 + r;
        int orig = perm[prow];
        if (orig < 0) continue;
#pragma unroll
        for (int j = 0; j < 4; ++j) {
          int col = wn + j * 16 + lr;   // tn0 == 0 for layer 2
          if (col < NC)
            Out[(size_t)orig * NC + col] = acc[i][j][r] + bv[col];
        }
      }
    }
  }
}

// ---------------------------------------------------------------------------
// Workspace layout (bytes):
//   perm   int[9216]                 @ 0          (36864)
//   starts int[9]                    @ 36864
//   XP     bf16[9216*1024]           @ 65536      (18874368)
//   W1T    bf16[8*1024*1024]         @ 18939904   (16777216)
//   W2T    bf16[8*128*1024]          @ 35717120   (2097152)
//   HB     bf16[9216*1024]           @ 37814272   (18874368)
//   total 56688640 (~54 MB)
// ---------------------------------------------------------------------------
extern "C" void kernel_launch(void* const* d_in, const int* in_sizes, int n_in,
                              void* d_out, int out_size, void* d_ws, size_t ws_size,
                              hipStream_t stream) {
  const float* x       = (const float*)d_in[0];
  const int*   task_id = (const int*)d_in[1];
  const float* W1      = (const float*)d_in[2];
  const float* b1      = (const float*)d_in[3];
  const float* W2      = (const float*)d_in[4];
  const float* b2      = (const float*)d_in[5];
  float* out = (float*)d_out;

  char* ws = (char*)d_ws;
  int* perm   = (int*)(ws + 0);
  int* starts = (int*)(ws + 36864);
  unsigned short* XP  = (unsigned short*)(ws + 65536);
  unsigned short* W1T = (unsigned short*)(ws + 18939904);
  unsigned short* W2T = (unsigned short*)(ws + 35717120);
  unsigned short* HB  = (unsigned short*)(ws + 37814272);

  bucket_kernel<<<1, 256, 0, stream>>>(task_id, perm, starts);
  gather_x<<<MPAD, 256, 0, stream>>>(x, perm, XP);
  transpose_w1<<<dim3(16, 16, T_TASKS), 256, 0, stream>>>(W1, W1T);
  transpose_w2<<<dim3(2, 16, T_TASKS), 256, 0, stream>>>(W2, W2T);
  gemm_k<HID, false><<<dim3(MTILES, HID / 128), 256, 0, stream>>>(
      XP, W1T, b1, starts, perm, HB, nullptr);
  gemm_k<NCP, true><<<dim3(MTILES, 1), 256, 0, stream>>>(
      HB, W2T, b2, starts, perm, nullptr, out);
}